// Round 5
// baseline (618.209 us; speedup 1.0000x reference)
//
#include <hip/hip_runtime.h>
#include <math.h>

// GATv2 x3 + log_softmax for MI355X (gfx950).
// Round 4 (resubmit; prior bench was GPUAcquisitionTimeout):
//   layers 1&2 GEMMs on MFMA via split-bf16 (Ah+Al)@(Bh+Bl), 3 terms.
//   - W pre-transposed+split to bf16 [m][k] once per call (L1/L2-resident)
//   - A loaded per-lane from global (8 contig f32), act+split in regs, no LDS
//   - acc fp32 in MFMA; stores guarded for the row tail
// Edge phase (CSR + fused online-softmax) unchanged from round 3.

#define TPB 256

typedef __attribute__((ext_vector_type(8))) short short8v;   // 8 bf16
typedef __attribute__((ext_vector_type(4))) float f32x4;

__device__ __forceinline__ short bf16rne(float v, float* recon) {
  unsigned u = __float_as_uint(v);
  unsigned r = (u + 0x7FFFu + ((u >> 16) & 1u)) >> 16;
  if (recon) *recon = __uint_as_float(r << 16);
  return (short)r;
}

// ---------------- W preprocess: W[k][m] f32 -> hi/lo bf16 [m][k] ----------------
__global__ void k_prepW(const float* __restrict__ W, short* __restrict__ hi,
                        short* __restrict__ lo, int K, int M) {
  int t = blockIdx.x * blockDim.x + threadIdx.x;
  if (t >= K * M) return;
  int k = t / M, m = t - k * M;
  float v = W[t];
  float vh;
  short h = bf16rne(v, &vh);
  short l = bf16rne(v - vh, nullptr);
  hi[m * K + k] = h;
  lo[m * K + k] = l;
}

// ---------------- MFMA GEMM: gl = act(x)@Wl, gr = act(x)@Wr  (K=128, M=128) ----
// block = 256 thr = 4 waves; wave w owns rows blockIdx.x*64 + w*16 .. +15.
// A-frag: row = lane&15, k = kstep + 8*(lane>>4) + j
// C-frag: col = lane&15, row = 4*(lane>>4) + j
template <int ACT>
__global__ __launch_bounds__(256) void k_gemm_mfma(
    const float* __restrict__ x,
    const short* __restrict__ blh, const short* __restrict__ bll,
    const short* __restrict__ brh, const short* __restrict__ brl,
    float* __restrict__ gl, float* __restrict__ gr, int n) {
  const int K = 128;
  int lane = threadIdx.x & 63;
  int w = threadIdx.x >> 6;
  int rbase = blockIdx.x * 64 + w * 16;
  int arow = rbase + (lane & 15);
  if (arow >= n) arow = n - 1;  // clamp; stores are guarded
  int koff = (lane >> 4) * 8;

  f32x4 acc[2][8];
#pragma unroll
  for (int m = 0; m < 2; ++m)
#pragma unroll
    for (int c = 0; c < 8; ++c) acc[m][c] = (f32x4)(0.f);

  int bbase = (lane & 15) * K + koff;  // + c*16*K + k0

#pragma unroll
  for (int k0 = 0; k0 < K; k0 += 32) {
    // ---- A fragment: load 8 contiguous f32, activate, split hi/lo ----
    const float4* px = reinterpret_cast<const float4*>(x + (size_t)arow * K + k0 + koff);
    float4 a0 = px[0], a1 = px[1];
    float av[8] = {a0.x, a0.y, a0.z, a0.w, a1.x, a1.y, a1.z, a1.w};
    short8v ah, al;
#pragma unroll
    for (int j = 0; j < 8; ++j) {
      float v = av[j];
      if (ACT == 1) v = v > 0.f ? v : (__expf(v) - 1.f);
      else if (ACT == 2) v = fmaxf(v, 0.f);
      float vh;
      ah[j] = bf16rne(v, &vh);
      al[j] = bf16rne(v - vh, nullptr);
    }
    // ---- B fragments + 3-term MFMA, both matrices ----
#pragma unroll
    for (int c = 0; c < 8; ++c) {
      int off = c * 16 * K + bbase + k0;
      short8v bh = *reinterpret_cast<const short8v*>(blh + off);
      short8v bl = *reinterpret_cast<const short8v*>(bll + off);
      acc[0][c] = __builtin_amdgcn_mfma_f32_16x16x32_bf16(ah, bh, acc[0][c], 0, 0, 0);
      acc[0][c] = __builtin_amdgcn_mfma_f32_16x16x32_bf16(ah, bl, acc[0][c], 0, 0, 0);
      acc[0][c] = __builtin_amdgcn_mfma_f32_16x16x32_bf16(al, bh, acc[0][c], 0, 0, 0);
      short8v ch = *reinterpret_cast<const short8v*>(brh + off);
      short8v cl = *reinterpret_cast<const short8v*>(brl + off);
      acc[1][c] = __builtin_amdgcn_mfma_f32_16x16x32_bf16(ah, ch, acc[1][c], 0, 0, 0);
      acc[1][c] = __builtin_amdgcn_mfma_f32_16x16x32_bf16(ah, cl, acc[1][c], 0, 0, 0);
      acc[1][c] = __builtin_amdgcn_mfma_f32_16x16x32_bf16(al, ch, acc[1][c], 0, 0, 0);
    }
  }

  // ---- store ----
  int crow = rbase + (lane >> 4) * 4;
  int ccol = lane & 15;
#pragma unroll
  for (int c = 0; c < 8; ++c)
#pragma unroll
    for (int j = 0; j < 4; ++j) {
      int r = crow + j;
      if (r < n) {
        gl[(size_t)r * 128 + c * 16 + ccol] = acc[0][c][j];
        gr[(size_t)r * 128 + c * 16 + ccol] = acc[1][c][j];
      }
    }
}

// ---------------- vector GEMM (layer 3): gl = act(x)@Wl, gr = act(x)@Wr --------
template <int K, int M, int NB, int ACT>
__global__ void k_gemm(const float* __restrict__ x, const float* __restrict__ Wl,
                       const float* __restrict__ Wr, float* __restrict__ gl,
                       float* __restrict__ gr, int n) {
  __shared__ float xs[NB][K];
  int base = blockIdx.x * NB;
  for (int i = threadIdx.x; i < NB * K; i += blockDim.x) {
    int r = i / K, k = i - r * K;
    int node = base + r;
    float v = (node < n) ? x[(size_t)node * K + k] : 0.f;
    if (ACT == 1) v = v > 0.f ? v : (__expf(v) - 1.f);
    else if (ACT == 2) v = fmaxf(v, 0.f);
    xs[r][k] = v;
  }
  __syncthreads();
  for (int m = threadIdx.x; m < M; m += blockDim.x) {
    float accl[NB], accr[NB];
#pragma unroll
    for (int r = 0; r < NB; ++r) { accl[r] = 0.f; accr[r] = 0.f; }
    for (int k = 0; k < K; ++k) {
      float wl = Wl[(size_t)k * M + m];
      float wr = Wr[(size_t)k * M + m];
#pragma unroll
      for (int r = 0; r < NB; ++r) {
        accl[r] = fmaf(xs[r][k], wl, accl[r]);
        accr[r] = fmaf(xs[r][k], wr, accr[r]);
      }
    }
#pragma unroll
    for (int r = 0; r < NB; ++r) {
      int node = base + r;
      if (node < n) {
        gl[(size_t)node * M + m] = accl[r];
        gr[(size_t)node * M + m] = accr[r];
      }
    }
  }
}

// ---------------- CSR build ----------------
__global__ void k_hist(const int* __restrict__ dst, int* __restrict__ cnt, int E) {
  int e = blockIdx.x * blockDim.x + threadIdx.x;
  if (e < E) atomicAdd(&cnt[dst[e]], 1);
}

__global__ void k_scan(const int* __restrict__ cnt, int* __restrict__ rowptr, int n) {
  const int T = 1024;
  __shared__ int wsum[16];
  __shared__ int carry_s;
  int lane = threadIdx.x & 63, wid = threadIdx.x >> 6;
  if (threadIdx.x == 0) carry_s = 0;
  __syncthreads();
  for (int base = 0; base < n; base += T) {
    int i = base + threadIdx.x;
    int v = (i < n) ? cnt[i] : 0;
    int x = v;
#pragma unroll
    for (int off = 1; off < 64; off <<= 1) {
      int t = __shfl_up(x, off);
      if (lane >= off) x += t;
    }
    if (lane == 63) wsum[wid] = x;
    __syncthreads();
    if (wid == 0) {
      int w = (lane < 16) ? wsum[lane] : 0;
#pragma unroll
      for (int off = 1; off < 16; off <<= 1) {
        int t = __shfl_up(w, off);
        if (lane >= off) w += t;
      }
      if (lane < 16) wsum[lane] = w;
    }
    __syncthreads();
    int woff = (wid > 0) ? wsum[wid - 1] : 0;
    if (i < n) rowptr[i] = carry_s + woff + x - v;
    __syncthreads();
    if (threadIdx.x == T - 1) carry_s += wsum[15];
    __syncthreads();
  }
  if (threadIdx.x == 0) rowptr[n] = carry_s;
}

__global__ void k_fill(const int* __restrict__ src, const int* __restrict__ dst,
                       int* __restrict__ cur, int* __restrict__ csr_src, int E) {
  int e = blockIdx.x * blockDim.x + threadIdx.x;
  if (e >= E) return;
  int pos = atomicAdd(&cur[dst[e]], 1);
  csr_src[pos] = src[e];
}

// ---------------- fused per-dst edge kernel, H=4 F=32 (HF=128) ----------------
__global__ void k_edge4(const float* __restrict__ gl, const float* __restrict__ gr,
                        const float* __restrict__ att, const int* __restrict__ rowptr,
                        const int* __restrict__ csr_src, float* __restrict__ out, int n) {
  int wid = (int)((blockIdx.x * blockDim.x + threadIdx.x) >> 6);
  if (wid >= n) return;
  int lane = threadIdx.x & 63;
  int p0 = rowptr[wid], p1 = rowptr[wid + 1];
  float2* po = reinterpret_cast<float2*>(out + (size_t)wid * 128);
  if (p1 <= p0) { po[lane] = make_float2(0.f, 0.f); return; }
  const float2 grv = reinterpret_cast<const float2*>(gr + (size_t)wid * 128)[lane];
  const float2 attv = reinterpret_cast<const float2*>(att)[lane];

  float m[4], l[4];
  float2 acc[4];
#pragma unroll
  for (int j = 0; j < 4; ++j) { m[j] = -INFINITY; l[j] = 0.f; acc[j] = make_float2(0.f, 0.f); }

#define UPD4(J, G)                                                     \
  {                                                                    \
    float vx = (G).x + grv.x; vx = vx > 0.f ? vx : 0.2f * vx;          \
    float vy = (G).y + grv.y; vy = vy > 0.f ? vy : 0.2f * vy;          \
    float part = fmaf(vx, attv.x, vy * attv.y);                        \
    part += __shfl_xor(part, 1);                                       \
    part += __shfl_xor(part, 2);                                       \
    part += __shfl_xor(part, 4);                                       \
    part += __shfl_xor(part, 8);                                       \
    float mn = fmaxf(m[J], part);                                      \
    float sc = __expf(m[J] - mn);                                      \
    float w = __expf(part - mn);                                       \
    l[J] = l[J] * sc + w;                                              \
    acc[J].x = fmaf(acc[J].x, sc, w * (G).x);                          \
    acc[J].y = fmaf(acc[J].y, sc, w * (G).y);                          \
    m[J] = mn;                                                         \
  }

  for (int base = p0; base < p1; base += 64) {
    int nv = p1 - base; if (nv > 64) nv = 64;
    int sv = (base + lane < p1) ? csr_src[base + lane] : 0;
    int i = 0;
    for (; i + 4 <= nv; i += 4) {
      int s0 = __shfl(sv, i + 0);
      int s1 = __shfl(sv, i + 1);
      int s2 = __shfl(sv, i + 2);
      int s3 = __shfl(sv, i + 3);
      float2 g0 = reinterpret_cast<const float2*>(gl + ((size_t)s0 << 7))[lane];
      float2 g1 = reinterpret_cast<const float2*>(gl + ((size_t)s1 << 7))[lane];
      float2 g2 = reinterpret_cast<const float2*>(gl + ((size_t)s2 << 7))[lane];
      float2 g3 = reinterpret_cast<const float2*>(gl + ((size_t)s3 << 7))[lane];
      UPD4(0, g0);
      UPD4(1, g1);
      UPD4(2, g2);
      UPD4(3, g3);
    }
    for (; i < nv; ++i) {
      int s0 = __shfl(sv, i);
      float2 g0 = reinterpret_cast<const float2*>(gl + ((size_t)s0 << 7))[lane];
      UPD4(0, g0);
    }
  }
#undef UPD4

  float mn = fmaxf(fmaxf(m[0], m[1]), fmaxf(m[2], m[3]));
  float lt = 0.f;
  float2 at = make_float2(0.f, 0.f);
#pragma unroll
  for (int j = 0; j < 4; ++j) {
    float sc = __expf(m[j] - mn);
    lt = fmaf(l[j], sc, lt);
    at.x = fmaf(acc[j].x, sc, at.x);
    at.y = fmaf(acc[j].y, sc, at.y);
  }
  float inv = 1.f / (lt + 1e-16f);
  po[lane] = make_float2(at.x * inv, at.y * inv);
}

// ---------------- fused per-dst edge kernel, H=1 F=40 ----------------
__global__ void k_edge1(const float* __restrict__ gl, const float* __restrict__ gr,
                        const float* __restrict__ att, const int* __restrict__ rowptr,
                        const int* __restrict__ csr_src, float* __restrict__ out, int n) {
  int wid = (int)((blockIdx.x * blockDim.x + threadIdx.x) >> 6);
  if (wid >= n) return;
  int lane = threadIdx.x & 63;
  bool actl = lane < 40;
  int p0 = rowptr[wid], p1 = rowptr[wid + 1];
  if (p1 <= p0) { if (actl) out[(size_t)wid * 40 + lane] = 0.f; return; }
  float grv = actl ? gr[(size_t)wid * 40 + lane] : 0.f;
  float attv = actl ? att[lane] : 0.f;

  float m[2], l[2], acc[2];
#pragma unroll
  for (int j = 0; j < 2; ++j) { m[j] = -INFINITY; l[j] = 0.f; acc[j] = 0.f; }

#define UPD1(J, G)                                                     \
  {                                                                    \
    float v = (G) + grv; v = v > 0.f ? v : 0.2f * v;                   \
    float part = v * attv;                                             \
    part += __shfl_xor(part, 1);                                       \
    part += __shfl_xor(part, 2);                                       \
    part += __shfl_xor(part, 4);                                       \
    part += __shfl_xor(part, 8);                                       \
    part += __shfl_xor(part, 16);                                      \
    part += __shfl_xor(part, 32);                                      \
    float mn = fmaxf(m[J], part);                                      \
    float sc = __expf(m[J] - mn);                                      \
    float w = __expf(part - mn);                                       \
    l[J] = l[J] * sc + w;                                              \
    acc[J] = fmaf(acc[J], sc, w * (G));                                \
    m[J] = mn;                                                         \
  }

  for (int base = p0; base < p1; base += 64) {
    int nv = p1 - base; if (nv > 64) nv = 64;
    int sv = (base + lane < p1) ? csr_src[base + lane] : 0;
    int i = 0;
    for (; i + 2 <= nv; i += 2) {
      int s0 = __shfl(sv, i + 0);
      int s1 = __shfl(sv, i + 1);
      float g0 = actl ? gl[(size_t)s0 * 40 + lane] : 0.f;
      float g1 = actl ? gl[(size_t)s1 * 40 + lane] : 0.f;
      UPD1(0, g0);
      UPD1(1, g1);
    }
    for (; i < nv; ++i) {
      int s0 = __shfl(sv, i);
      float g0 = actl ? gl[(size_t)s0 * 40 + lane] : 0.f;
      UPD1(0, g0);
    }
  }
#undef UPD1

  float mn = fmaxf(m[0], m[1]);
  float s0 = __expf(m[0] - mn), s1 = __expf(m[1] - mn);
  float lt = l[0] * s0 + l[1] * s1;
  float at = acc[0] * s0 + acc[1] * s1;
  float inv = 1.f / (lt + 1e-16f);
  if (actl) out[(size_t)wid * 40 + lane] = at * inv;
}

// ---------------- row-wise log_softmax over C=40 ----------------
__global__ void k_logsoftmax(const float* __restrict__ in, float* __restrict__ out,
                             int n, int C) {
  int node = blockIdx.x;
  int t = threadIdx.x;
  float v = (t < C) ? in[(size_t)node * C + t] : -INFINITY;
  float mx = v;
#pragma unroll
  for (int o = 32; o > 0; o >>= 1) mx = fmaxf(mx, __shfl_xor(mx, o));
  float ex = (t < C) ? __expf(v - mx) : 0.f;
  float sm = ex;
#pragma unroll
  for (int o = 32; o > 0; o >>= 1) sm += __shfl_xor(sm, o);
  if (t < C) out[(size_t)node * C + t] = v - mx - logf(sm);
}

static inline int cdiv(long long a, int b) { return (int)((a + b - 1) / b); }

extern "C" void kernel_launch(void* const* d_in, const int* in_sizes, int n_in,
                              void* d_out, int out_size, void* d_ws, size_t ws_size,
                              hipStream_t stream) {
  const float* x    = (const float*)d_in[0];
  const float* Wl1  = (const float*)d_in[1];
  const float* Wr1  = (const float*)d_in[2];
  const float* att1 = (const float*)d_in[3];
  const float* Wl2  = (const float*)d_in[4];
  const float* Wr2  = (const float*)d_in[5];
  const float* att2 = (const float*)d_in[6];
  const float* Wl3  = (const float*)d_in[7];
  const float* Wr3  = (const float*)d_in[8];
  const float* att3 = (const float*)d_in[9];
  const int*   ei   = (const int*)d_in[10];

  const int N = in_sizes[0] / 128;   // 50000
  const int E = in_sizes[10] / 2;    // 800000
  const int* src = ei;
  const int* dst = ei + E;

  // workspace layout (Wt arrays first for 16B alignment of short8 loads)
  short* wt = (short*)d_ws;  // 8 arrays x 16384 shorts (l1h,l1l,r1h,r1l,l2h,l2l,r2h,r2l)
  short* wl1h = wt +  0 * 16384;  short* wl1l = wt + 1 * 16384;
  short* wr1h = wt +  2 * 16384;  short* wr1l = wt + 3 * 16384;
  short* wl2h = wt +  4 * 16384;  short* wl2l = wt + 5 * 16384;
  short* wr2h = wt +  6 * 16384;  short* wr2l = wt + 7 * 16384;
  float* ws     = (float*)d_ws + 65536;
  float* bufA   = ws;                             // N*128
  float* bufGL  = bufA + (size_t)N * 128;         // N*128
  float* bufGR  = bufGL + (size_t)N * 128;        // N*128
  float* out3   = bufGR + (size_t)N * 128;        // N*40
  int*   cnt    = (int*)(out3 + (size_t)N * 40);  // N
  int*   rowptr = cnt + N;                        // N+1
  int*   cur    = rowptr + N + 1;                 // N
  int*   csrS   = cur + N;                        // E

  float* outf = (float*)d_out;

  // ---------------- CSR build + W preprocess ----------------
  hipMemsetAsync(cnt, 0, (size_t)N * sizeof(int), stream);
  k_hist<<<cdiv(E, TPB), TPB, 0, stream>>>(dst, cnt, E);
  k_prepW<<<cdiv(128 * 128, TPB), TPB, 0, stream>>>(Wl1, wl1h, wl1l, 128, 128);
  k_prepW<<<cdiv(128 * 128, TPB), TPB, 0, stream>>>(Wr1, wr1h, wr1l, 128, 128);
  k_prepW<<<cdiv(128 * 128, TPB), TPB, 0, stream>>>(Wl2, wl2h, wl2l, 128, 128);
  k_prepW<<<cdiv(128 * 128, TPB), TPB, 0, stream>>>(Wr2, wr2h, wr2l, 128, 128);
  k_scan<<<1, 1024, 0, stream>>>(cnt, rowptr, N);
  hipMemcpyAsync(cur, rowptr, (size_t)N * sizeof(int), hipMemcpyDeviceToDevice, stream);
  k_fill<<<cdiv(E, TPB), TPB, 0, stream>>>(src, dst, cur, csrS, E);

  // ---------------- layer 1 (input x, no input act) ----------------
  k_gemm_mfma<0><<<cdiv(N, 64), 256, 0, stream>>>(x, wl1h, wl1l, wr1h, wr1l, bufGL, bufGR, N);
  k_edge4<<<cdiv(N, 4), TPB, 0, stream>>>(bufGL, bufGR, att1, rowptr, csrS, bufA, N);

  // ---------------- layer 2 (input bufA with ELU) ----------------
  k_gemm_mfma<1><<<cdiv(N, 64), 256, 0, stream>>>(bufA, wl2h, wl2l, wr2h, wr2l, bufGL, bufGR, N);
  k_edge4<<<cdiv(N, 4), TPB, 0, stream>>>(bufGL, bufGR, att2, rowptr, csrS, bufA, N);

  // ---------------- layer 3 (input bufA with ReLU, H=1, F=40) ----------------
  k_gemm<128, 40, 16, 2><<<cdiv(N, 16), 128, 0, stream>>>(bufA, Wl3, Wr3, bufGL, bufGR, N);
  k_edge1<<<cdiv(N, 4), TPB, 0, stream>>>(bufGL, bufGR, att3, rowptr, csrS, out3, N);

  // ---------------- log_softmax ----------------
  k_logsoftmax<<<N, 64, 0, stream>>>(out3, outf, N, 40);
}